// Round 3
// baseline (363.976 us; speedup 1.0000x reference)
//
#include <hip/hip_runtime.h>
#include <math.h>
#include <stdint.h>

// Problem constants (B,C,H,W) = (16,20,256,256), fp32 in, 4 fp32 scalars out.
constexpr int Bn = 16, Cn = 20, Hn = 256, Wn = 256;
constexpr int BCn = Bn * Cn;                 // 320 slices
constexpr int HWn = Hn * Wn;                 // 65536 per slice
constexpr int SPLIT = 4;                     // blocks per slice
constexpr int NBLK = BCn * SPLIT;            // 1280 blocks = exactly 5/CU, zero tail
constexpr int CHUNK = HWn / SPLIT;           // 16384 elems per block
constexpr int TPB = 256;                     // 4 waves
constexpr int STEPS = CHUNK / 4 / 256;       // 16 steps/wave, 256 elems (1 KB) each
constexpr int DEPTH = 3;                     // LDS pipeline depth (3 pairs = 6 KB in flight/wave)
constexpr int NSLOT = 10;
// ws layout TRANSPOSED: ws[slot * NBLK + blk]  (needs NBLK*NSLOT*4 = 51.2 KB)
// slots: 0 mass, 1 sum(t*y), 2 sum(t*x), 3 sum(p), 4 sum(p*y), 5 sum(p*x),
//        6 sum(p*(y^2+x^2)), 7 SUM(at*om^2*log2(pt)) [x ln2, negated in finalize],
//        8 (pred-t)^2, 9 |pred|

typedef const __attribute__((address_space(1))) void* gld_gptr;
typedef __attribute__((address_space(3))) void* gld_lptr;

__device__ inline float wave_reduce(float v) {
    #pragma unroll
    for (int o = 32; o > 0; o >>= 1) v += __shfl_down(v, o, 64);
    return v;
}

// Latency coverage via LDS-DMA, not VGPRs: global_load_lds carries the payload
// (zero registers), each wave keeps 3 pred+target pairs (6 KB) in flight with
// counted vmcnt drain. Buffers are wave-private -> no barriers in the main loop.
// R0/R2 both pinned at ~2.6 TB/s because register-held prefetch can't go deep
// without crossing the 64-VGPR occupancy cliff (R1: spill disaster).
__global__ __launch_bounds__(TPB, 5) void partials_kernel(
        const float* __restrict__ pred, const float* __restrict__ target,
        float* __restrict__ ws) {
    __shared__ float lp[4][DEPTH][256];      // 12 KB  (wave-private pred tiles)
    __shared__ float lt[4][DEPTH][256];      // 12 KB  (wave-private target tiles)
    __shared__ float red[TPB / 64][NSLOT];

    const int blk = blockIdx.x;
    const int bc = blk >> 2;                 // / SPLIT
    const int chunk = blk & (SPLIT - 1);
    const int tid = threadIdx.x;
    const int lane = tid & 63, wave = tid >> 6;

    // Wave handles 4096 consecutive elems = 16 rows of W=256.
    // e = chunk*16384 + wave*4096 + step*256 + lane*4:
    //   x = lane*4 + j   (lane-constant -> fold x-moments at the end)
    //   y = chunk*64 + wave*16 + step   (wave-uniform per step)
    const long long ebase = (long long)bc * HWn + chunk * CHUNK
                          + wave * (CHUNK / 4) + lane * 4;
    const float* gp = pred + ebase;
    const float* gt = target + ebase;

    auto ISSUE = [&](int s) {                // s is compile-time under full unroll
        const int b = s % DEPTH;
        __builtin_amdgcn_global_load_lds((gld_gptr)(gp + s * 256),
                                         (gld_lptr)(&lp[wave][b][0]), 16, 0, 0);
        __builtin_amdgcn_global_load_lds((gld_gptr)(gt + s * 256),
                                         (gld_lptr)(&lt[wave][b][0]), 16, 0, 0);
    };

    ISSUE(0); ISSUE(1); ISSUE(2);            // prologue: 6 loads in flight

    float a_mass = 0.f, a_ty = 0.f, a_jt = 0.f, a_p = 0.f, a_py = 0.f,
          a_jp = 0.f, a_pyy = 0.f, a_j2p = 0.f, a_foc = 0.f, a_sq = 0.f,
          a_abs = 0.f;
    const float ybase = (float)(chunk * 64 + wave * STEPS);
    const float x0 = (float)(lane * 4);
    constexpr float L2E = 1.44269504088896f; // log2(e)

    #pragma unroll
    for (int s = 0; s < STEPS; s++) {
        // counted drain: never vmcnt(0) in steady state (T4)
        if (s < STEPS - 2)       asm volatile("s_waitcnt vmcnt(4)" ::: "memory");
        else if (s == STEPS - 2) asm volatile("s_waitcnt vmcnt(2)" ::: "memory");
        else                     asm volatile("s_waitcnt vmcnt(0)" ::: "memory");
        const int b = s % DEPTH;
        const float4 pv = *(const float4*)&lp[wave][b][lane * 4];
        const float4 tv = *(const float4*)&lt[wave][b][lane * 4];
        // ds_reads must complete before the DMA below overwrites this buffer
        asm volatile("s_waitcnt lgkmcnt(0)" ::: "memory");
        if (s + DEPTH < STEPS) ISSUE(s + DEPTH);

        const float yf = ybase + (float)s;
        const float pv4[4] = {pv.x, pv.y, pv.z, pv.w};
        const float tv4[4] = {tv.x, tv.y, tv.z, tv.w};
        float st4 = 0.f, sp4 = 0.f;
        #pragma unroll
        for (int j = 0; j < 4; j++) {
            const float v = pv4[j];
            const float t = tv4[j];          // exactly 0.0 or 1.0
            // sigmoid + focal in log2 domain (ln2 applied once in finalize):
            // u = v*log2(e); 1-p = e^{-v}*p -> log2(pt) = log2(p) - (1-t)*u
            const float u  = v * L2E;
            const float e  = __builtin_amdgcn_exp2f(-u);
            const float p  = __builtin_amdgcn_rcpf(1.0f + e);   // sigmoid
            const float l2p = __builtin_amdgcn_logf(p);         // log2(p)
            const float l2pt = fmaf(t, u, l2p - u);
            const float om = fmaf(t, fmaf(p, -2.0f, 1.0f), p);  // 1 - pt
            const float at = fmaf(t, -0.5f, 0.75f);             // alpha_t
            a_foc = fmaf(at * l2pt, om * om, a_foc);
            const float d = v - t;
            a_sq = fmaf(d, d, a_sq);
            a_abs += fabsf(v);
            st4 += t;
            sp4 += p;
            if (j == 1)      { a_jt += t;               a_jp += p;               a_j2p += p; }
            else if (j == 2) { a_jt = fmaf(t, 2.f, a_jt); a_jp = fmaf(p, 2.f, a_jp); a_j2p = fmaf(p, 4.f, a_j2p); }
            else if (j == 3) { a_jt = fmaf(t, 3.f, a_jt); a_jp = fmaf(p, 3.f, a_jp); a_j2p = fmaf(p, 9.f, a_j2p); }
        }
        a_mass += st4;
        a_ty  = fmaf(st4, yf, a_ty);
        a_p   += sp4;
        a_py  = fmaf(sp4, yf, a_py);
        a_pyy = fmaf(sp4, yf * yf, a_pyy);
    }

    // Fold lane-constant x moments: x = x0 + j
    float slot[NSLOT];
    slot[0] = a_mass;
    slot[1] = a_ty;
    slot[2] = fmaf(x0, a_mass, a_jt);                        // sum t*x
    slot[3] = a_p;
    slot[4] = a_py;
    slot[5] = fmaf(x0, a_p, a_jp);                           // sum p*x
    slot[6] = a_pyy + x0 * x0 * a_p + 2.f * x0 * a_jp + a_j2p; // sum p*(y^2+x^2)
    slot[7] = a_foc;
    slot[8] = a_sq;
    slot[9] = a_abs;

    #pragma unroll
    for (int k = 0; k < NSLOT; k++) {
        const float r = wave_reduce(slot[k]);
        if (lane == 0) red[wave][k] = r;
    }
    __syncthreads();
    if (tid < NSLOT) {
        float s = 0.f;
        #pragma unroll
        for (int w = 0; w < TPB / 64; w++) s += red[w][tid];
        ws[tid * NBLK + blk] = s;            // transposed store
    }
}

// 320 threads: thread tid owns slice (b,c)=tid. With SPLIT=4 and transposed ws,
// each slot's 4 partials for a slice are exactly one float4 -> 10 vector loads.
__global__ __launch_bounds__(320) void finalize_kernel(
        const float* __restrict__ ws, float* __restrict__ out) {
    const int tid = threadIdx.x;
    const float4* __restrict__ w4 = (const float4*)ws;

    float s[NSLOT];
    #pragma unroll
    for (int k = 0; k < NSLOT; k++) {
        const float4 v = w4[k * (NBLK / 4) + tid];
        s[k] = v.x + v.y + v.z + v.w;
    }

    // ---- per-(b,c) concentration term ----
    const float mass = s[0];
    const bool valid = mass > 0.f;
    const float sm = valid ? mass : 1.0f;
    const float cy = s[1] / sm, cx = s[2] / sm;
    const float pdsq = s[6] - 2.f * cy * s[4] - 2.f * cx * s[5]
                     + (cy * cy + cx * cx) * s[3];
    float vals[5];
    vals[0] = valid ? (pdsq / (float)HWn) : 0.f;   // conc per-sample mean
    vals[1] = valid ? 1.f : 0.f;                   // n_valid
    vals[2] = s[7];                                // focal sum (log2 domain)
    vals[3] = s[8];                                // sum (pred-t)^2
    vals[4] = s[9];                                // sum |pred|

    __shared__ float lds[5][5];
    const int lane = tid & 63, wave = tid >> 6;
    #pragma unroll
    for (int k = 0; k < 5; k++) {
        const float r = wave_reduce(vals[k]);
        if (lane == 0) lds[wave][k] = r;
    }
    __syncthreads();

    if (tid == 0) {
        float tot[5];
        #pragma unroll
        for (int k = 0; k < 5; k++) {
            float a = 0.f;
            #pragma unroll
            for (int w = 0; w < 5; w++) a += lds[w][k];
            tot[k] = a;
        }
        const float NTOT = (float)Bn * Cn * Hn * Wn;   // 20971520
        constexpr float LN2 = 0.69314718055994531f;
        const float focal = -LN2 * tot[2] / NTOT;      // restore ln from log2
        const float sparsity = tot[3] / NTOT + tot[4] / NTOT;
        const float concentration =
            (tot[1] > 0.f) ? (tot[0] / fmaxf(tot[1], 1.f)) : 0.f;
        const float total = 1.0f * focal + 0.8f * sparsity + 1.5f * concentration;
        out[0] = total;
        out[1] = focal;
        out[2] = sparsity;
        out[3] = concentration;
    }
}

extern "C" void kernel_launch(void* const* d_in, const int* in_sizes, int n_in,
                              void* d_out, int out_size, void* d_ws, size_t ws_size,
                              hipStream_t stream) {
    const float* pred   = (const float*)d_in[0];
    const float* target = (const float*)d_in[1];
    float* out = (float*)d_out;
    float* ws  = (float*)d_ws;   // needs NBLK*NSLOT*4 = 51.2 KB

    partials_kernel<<<NBLK, TPB, 0, stream>>>(pred, target, ws);
    finalize_kernel<<<1, 320, 0, stream>>>(ws, out);
}

// Round 5
// 186.783 us; speedup vs baseline: 1.9487x; 1.9487x over previous
//
#include <hip/hip_runtime.h>
#include <math.h>
#include <stdint.h>

// Problem constants (B,C,H,W) = (16,20,256,256), fp32 in, 4 fp32 scalars out.
constexpr int Bn = 16, Cn = 20, Hn = 256, Wn = 256;
constexpr int BCn = Bn * Cn;                 // 320 slices
constexpr int HWn = Hn * Wn;                 // 65536 per slice
constexpr int SPLIT = 4;                     // blocks per slice
constexpr int NBLK = BCn * SPLIT;            // 1280 blocks = exactly 5/CU, zero tail
constexpr int CHUNK = HWn / SPLIT;           // 16384 elems per block
constexpr int TPB = 256;                     // 4 waves
constexpr int WCHUNK = CHUNK / 4;            // 4096 elems per wave = 16 rows
constexpr int STEPS = WCHUNK / 256;          // 16 steps, 256 elems (1 KB) each
constexpr int DEPTH = 4;                     // LDS ring depth: 6 loads (6 KB) in flight/wave
constexpr int NSLOT = 10;
// ws layout TRANSPOSED: ws[slot * NBLK + blk]  (needs NSLOT*NBLK*4 = 51.2 KB)
// slots: 0 mass, 1 sum(t*y), 2 sum(t*x), 3 sum(p), 4 sum(p*y), 5 sum(p*x),
//        6 sum(p*(y^2+x^2)), 7 SUM(at*om^2*log2(pt)) [x ln2, negated in finalize],
//        8 (pred-t)^2, 9 |pred|
//
// R4 post-mortem: fused last-block finalize + dropped lgkmcnt(0) ring guard
// failed absmax=448 (~2.7%). Reverted BOTH to the verified envelope:
//   - two kernels (R0-R3 structure, always absmax 0)
//   - per-step lgkmcnt(0) before DMA re-issue (R3 passed with it; the DEPTH=4
//     write target is the buffer read only ONE step earlier, so the guard is
//     required, not optional)
// Kept from R4: rolling #pragma unroll 1 loop with loop-carried pointers --
// this is the fix for R3's real problem (full unroll -> 287 MB accumulator
// spill, VALUBusy 5.8%).

typedef const __attribute__((address_space(1))) void* gld_gptr;
typedef __attribute__((address_space(3))) void* gld_lptr;

__device__ inline float wave_reduce(float v) {
    #pragma unroll
    for (int o = 32; o > 0; o >>= 1) v += __shfl_down(v, o, 64);
    return v;
}

__global__ __launch_bounds__(TPB) void partials_kernel(
        const float* __restrict__ pred, const float* __restrict__ target,
        float* __restrict__ ws) {
    __shared__ float lp[4][DEPTH][256];      // 16 KB (wave-private pred ring)
    __shared__ float lt[4][DEPTH][256];      // 16 KB (wave-private target ring)
    __shared__ float red[TPB / 64][NSLOT];

    const int blk = blockIdx.x;
    const int bc = blk >> 2;                 // / SPLIT
    const int chunk = blk & (SPLIT - 1);
    const int tid = threadIdx.x;
    const int lane = tid & 63, wave = tid >> 6;

    // e = chunk*CHUNK + wave*WCHUNK + s*256 + lane*4 + j
    //   x = lane*4 + j (lane-constant), y = chunk*64 + wave*16 + s (wave-uniform)
    const long long ebase = (long long)bc * HWn + chunk * CHUNK
                          + wave * WCHUNK + lane * 4;
    const float* gpi = pred + ebase;         // issue pointers, roll +256/step
    const float* gti = target + ebase;
    float* lpw = &lp[wave][0][0];            // wave-uniform LDS ring bases
    float* ltw = &lt[wave][0][0];

    auto ISSUE = [&](int wb) {
        __builtin_amdgcn_global_load_lds((gld_gptr)gpi, (gld_lptr)(lpw + (wb << 8)), 16, 0, 0);
        __builtin_amdgcn_global_load_lds((gld_gptr)gti, (gld_lptr)(ltw + (wb << 8)), 16, 0, 0);
        gpi += 256; gti += 256;
    };

    ISSUE(0); ISSUE(1); ISSUE(2);            // prologue: 6 loads in flight

    float a_mass = 0.f, a_ty = 0.f, a_jt = 0.f, a_p = 0.f, a_py = 0.f,
          a_jp = 0.f, a_pyy = 0.f, a_j2p = 0.f, a_foc = 0.f, a_sq = 0.f,
          a_abs = 0.f;
    float yf = (float)(chunk * 64 + wave * STEPS);
    const float x0 = (float)(lane * 4);
    constexpr float L2E = 1.44269504088896f; // log2(e)
    int rbuf = 0, wbuf = 3;

    auto BODY = [&](int wait_n, bool do_issue) {
        if (wait_n == 4)      asm volatile("s_waitcnt vmcnt(4)" ::: "memory");
        else if (wait_n == 2) asm volatile("s_waitcnt vmcnt(2)" ::: "memory");
        else                  asm volatile("s_waitcnt vmcnt(0)" ::: "memory");
        const float4 pv = *(const float4*)(lpw + (rbuf << 8) + lane * 4);
        const float4 tv = *(const float4*)(ltw + (rbuf << 8) + lane * 4);
        rbuf = (rbuf + 1) & (DEPTH - 1);
        // Ring safety: this step's ds_reads must retire before any DMA that
        // could overwrite a recently-read buffer is issued (R4 dropped this
        // and failed correctness).
        asm volatile("s_waitcnt lgkmcnt(0)" ::: "memory");
        if (do_issue) { ISSUE(wbuf); wbuf = (wbuf + 1) & (DEPTH - 1); }

        const float pv4[4] = {pv.x, pv.y, pv.z, pv.w};
        const float tv4[4] = {tv.x, tv.y, tv.z, tv.w};
        float st4 = 0.f, sp4 = 0.f;
        #pragma unroll
        for (int j = 0; j < 4; j++) {
            const float v = pv4[j];
            const float t = tv4[j];          // exactly 0.0 or 1.0
            // sigmoid + focal in log2 domain (ln2 applied once in finalize):
            // u = v*log2(e); 1-p = e^{-v}*p -> log2(pt) = log2(p) - (1-t)*u
            const float u  = v * L2E;
            const float e  = __builtin_amdgcn_exp2f(-u);
            const float p  = __builtin_amdgcn_rcpf(1.0f + e);   // sigmoid
            const float l2p = __builtin_amdgcn_logf(p);         // log2(p)
            const float l2pt = fmaf(t, u, l2p - u);
            const float om = fmaf(t, fmaf(p, -2.0f, 1.0f), p);  // 1 - pt
            const float at = fmaf(t, -0.5f, 0.75f);             // alpha_t
            a_foc = fmaf(at * l2pt, om * om, a_foc);
            const float d = v - t;
            a_sq = fmaf(d, d, a_sq);
            a_abs += fabsf(v);
            st4 += t;
            sp4 += p;
            if (j == 1)      { a_jt += t;                 a_jp += p;                 a_j2p += p; }
            else if (j == 2) { a_jt = fmaf(t, 2.f, a_jt); a_jp = fmaf(p, 2.f, a_jp); a_j2p = fmaf(p, 4.f, a_j2p); }
            else if (j == 3) { a_jt = fmaf(t, 3.f, a_jt); a_jp = fmaf(p, 3.f, a_jp); a_j2p = fmaf(p, 9.f, a_j2p); }
        }
        a_mass += st4;
        a_ty  = fmaf(st4, yf, a_ty);
        a_p   += sp4;
        a_py  = fmaf(sp4, yf, a_py);
        a_pyy = fmaf(sp4, yf * yf, a_pyy);
        yf += 1.0f;
    };

    #pragma unroll 1
    for (int s = 0; s < STEPS - 3; s++) BODY(4, true);   // s = 0..12
    BODY(4, false); BODY(2, false); BODY(0, false);      // peeled tail 13,14,15

    // Fold lane-constant x moments: x = x0 + j
    float slot[NSLOT];
    slot[0] = a_mass;
    slot[1] = a_ty;
    slot[2] = fmaf(x0, a_mass, a_jt);                         // sum t*x
    slot[3] = a_p;
    slot[4] = a_py;
    slot[5] = fmaf(x0, a_p, a_jp);                            // sum p*x
    slot[6] = a_pyy + x0 * x0 * a_p + 2.f * x0 * a_jp + a_j2p;// sum p*(y^2+x^2)
    slot[7] = a_foc;
    slot[8] = a_sq;
    slot[9] = a_abs;

    #pragma unroll
    for (int k = 0; k < NSLOT; k++) {
        const float r = wave_reduce(slot[k]);
        if (lane == 0) red[wave][k] = r;
    }
    __syncthreads();
    if (tid < NSLOT) {
        float s = 0.f;
        #pragma unroll
        for (int w = 0; w < TPB / 64; w++) s += red[w][tid];
        ws[tid * NBLK + blk] = s;            // transposed store
    }
}

// 320 threads: thread tid owns slice (b,c)=tid. With SPLIT=4 and transposed ws,
// each slot's 4 partials for a slice are exactly one float4 -> 10 vector loads.
__global__ __launch_bounds__(320) void finalize_kernel(
        const float* __restrict__ ws, float* __restrict__ out) {
    const int tid = threadIdx.x;
    const float4* __restrict__ w4 = (const float4*)ws;

    float s[NSLOT];
    #pragma unroll
    for (int k = 0; k < NSLOT; k++) {
        const float4 v = w4[k * (NBLK / 4) + tid];
        s[k] = v.x + v.y + v.z + v.w;
    }

    // ---- per-(b,c) concentration term ----
    const float mass = s[0];
    const bool valid = mass > 0.f;
    const float sm = valid ? mass : 1.0f;
    const float cy = s[1] / sm, cx = s[2] / sm;
    const float pdsq = s[6] - 2.f * cy * s[4] - 2.f * cx * s[5]
                     + (cy * cy + cx * cx) * s[3];
    float vals[5];
    vals[0] = valid ? (pdsq / (float)HWn) : 0.f;   // conc per-sample mean
    vals[1] = valid ? 1.f : 0.f;                   // n_valid
    vals[2] = s[7];                                // focal sum (log2 domain)
    vals[3] = s[8];                                // sum (pred-t)^2
    vals[4] = s[9];                                // sum |pred|

    __shared__ float lds[5][5];
    const int lane = tid & 63, wave = tid >> 6;
    #pragma unroll
    for (int k = 0; k < 5; k++) {
        const float r = wave_reduce(vals[k]);
        if (lane == 0) lds[wave][k] = r;
    }
    __syncthreads();

    if (tid == 0) {
        float tot[5];
        #pragma unroll
        for (int k = 0; k < 5; k++) {
            float a = 0.f;
            #pragma unroll
            for (int w = 0; w < 5; w++) a += lds[w][k];
            tot[k] = a;
        }
        const float NTOT = (float)Bn * Cn * Hn * Wn;   // 20971520
        constexpr float LN2 = 0.69314718055994531f;
        const float focal = -LN2 * tot[2] / NTOT;      // restore ln from log2
        const float sparsity = tot[3] / NTOT + tot[4] / NTOT;
        const float concentration =
            (tot[1] > 0.f) ? (tot[0] / fmaxf(tot[1], 1.f)) : 0.f;
        const float total = 1.0f * focal + 0.8f * sparsity + 1.5f * concentration;
        out[0] = total;
        out[1] = focal;
        out[2] = sparsity;
        out[3] = concentration;
    }
}

extern "C" void kernel_launch(void* const* d_in, const int* in_sizes, int n_in,
                              void* d_out, int out_size, void* d_ws, size_t ws_size,
                              hipStream_t stream) {
    const float* pred   = (const float*)d_in[0];
    const float* target = (const float*)d_in[1];
    float* out = (float*)d_out;
    float* ws  = (float*)d_ws;   // needs NSLOT*NBLK*4 = 51.2 KB

    partials_kernel<<<NBLK, TPB, 0, stream>>>(pred, target, ws);
    finalize_kernel<<<1, 320, 0, stream>>>(ws, out);
}